// Round 1
// baseline (245.481 us; speedup 1.0000x reference)
//
#include <hip/hip_runtime.h>

// ---------------------------------------------------------------------------
// CrossAttention: B=8, T=S=1024, E=H=768, fp32 in/out, bf16 MFMA internally.
//
// Round 10: BK 64 -> 32 to double resident blocks/CU (latency/sync-bound per
// counters: MfmaUtil 19 / VALUBusy 16 / HBM 16% / Occ 15.5 -- nothing
// saturated). LDS 64KB -> 32KB (4 x 8KB buffers) => 4-5 blocks/CU instead of
// 2; __launch_bounds__(256,4). Per-tile MFMA halves (16/wave) but barrier
// stalls now overlap across 4-5 independent blocks.
// Swizzle re-derived for 64B rows: phys slot s = (k + (r>>1)) & 3; read
// sl = ((quad + (l16>>1)) & 3) * 8 -> uniform 8 dwords/bank (conflict-free
// floor). DMA source applies inverse perm: k = ((lane&3) - (lane>>3)) & 3
// (per-lane global source, linear LDS dest). vmcnt count 8 -> 4 per stage.
// ---------------------------------------------------------------------------

typedef __bf16 bf16x8 __attribute__((ext_vector_type(8)));
typedef float  f32x4  __attribute__((ext_vector_type(4)));

#define WAIT_VM4 __builtin_amdgcn_s_waitcnt(0x0F74)   // vmcnt(4), lgkm/exp nowait
#define WAIT_VM0 __builtin_amdgcn_s_waitcnt(0x0F70)   // vmcnt(0)
#define BAR      __builtin_amdgcn_s_barrier()

__device__ __forceinline__ unsigned short f2bf(float f) {
    unsigned int u = __float_as_uint(f);
    u += 0x7fffu + ((u >> 16) & 1u);   // RNE; inputs are finite
    return (unsigned short)(u >> 16);
}

__device__ __forceinline__ void async_copy16(const void* g, void* s) {
    __builtin_amdgcn_global_load_lds(
        (const __attribute__((address_space(1))) void*)g,
        (__attribute__((address_space(3))) void*)s, 16, 0, 0);
}

// Block computes C[row0:row0+128, col0:col0+128].
// Ag = A + row0*K ([*,K] bf16 row-major); Bg = B^T + col0*K ([*,K]).
// Exactly one of Cf/Cb non-null. transC: store C^T as [b][H][S] (vt).
__device__ __forceinline__ void gemm_core(
    const unsigned short* __restrict__ Ag,
    const unsigned short* __restrict__ Bg,
    const int K,
    float* __restrict__ Cf, unsigned short* __restrict__ Cb,
    const long ldc, const int transC, const float* __restrict__ bias,
    const float scale, const long row0, const long col0)
{
    __shared__ __align__(16) unsigned short As0[4096];   // [128][32] swizzled
    __shared__ __align__(16) unsigned short As1[4096];
    __shared__ __align__(16) unsigned short Bs0[4096];
    __shared__ __align__(16) unsigned short Bs1[4096];

    const int tid  = threadIdx.x;
    const int lane = tid & 63;
    const int quad = lane >> 4;
    const int l16  = lane & 15;
    const int wv   = tid >> 6;
    const int wm   = (wv >> 1) * 64;
    const int wn   = (wv & 1) * 64;

    // DMA staging: inst h, thread tid covers chunk c = h*256 + tid.
    // Dest row r = c>>2 (4 x 16B slots per 64B row), phys slot s = lane&3.
    // Stored k-chunk at (r,s) is k = (s - (r>>1)) & 3; since (wv*8, h*32)
    // vanish mod 4: k = ((lane&3) - (lane>>3)) & 3.
    const int j8 = ((((lane & 3) - (lane >> 3)) & 3)) * 8;  // src k-offset, elems
    const int rb = wv * 16 + (lane >> 2);                   // row for h=0
    const unsigned short* sa_src = Ag + (long)rb * K + j8;
    const unsigned short* sb_src = Bg + (long)rb * K + j8;
    const int dbase = (wv * 64 + lane) * 8;                 // LDS dst elems, h=0

    f32x4 acc[4][4];
#pragma unroll
    for (int i = 0; i < 4; ++i)
#pragma unroll
        for (int j = 0; j < 4; ++j)
            acc[i][j] = f32x4{0.f, 0.f, 0.f, 0.f};

    // one tile = 4 DMA instructions per thread (2 A + 2 B)
    auto stage = [&](unsigned short* dA, unsigned short* dB, int k0) {
#pragma unroll
        for (int h = 0; h < 2; ++h) {
            async_copy16(sa_src + (long)(h * 64) * K + k0, &dA[dbase + h * 2048]);
            async_copy16(sb_src + (long)(h * 64) * K + k0, &dB[dbase + h * 2048]);
        }
    };

    // 16 MFMA per wave per tile (single k-slab of 32)
    auto compute = [&](const unsigned short* sA, const unsigned short* sB) {
        bf16x8 af[4], bf[4];
        const int sl = ((quad + (l16 >> 1)) & 3) * 8;   // phys slot, elems
#pragma unroll
        for (int i = 0; i < 4; ++i) {
            af[i] = *(const bf16x8*)&sA[(wm + i * 16 + l16) * 32 + sl];
            bf[i] = *(const bf16x8*)&sB[(wn + i * 16 + l16) * 32 + sl];
        }
#pragma unroll
        for (int i = 0; i < 4; ++i)
#pragma unroll
            for (int j = 0; j < 4; ++j)
                acc[i][j] = __builtin_amdgcn_mfma_f32_16x16x32_bf16(
                    af[i], bf[j], acc[i][j], 0, 0, 0);
    };

    const int nk = K >> 5;            // 24 or 32: even, >= 4
    stage(As0, Bs0, 0);               // tile 0 -> buf0   (4 loads)
    stage(As1, Bs1, 32);              // tile 1 -> buf1   (4 loads)
    int k0 = 64;

    for (int t = 0; t < nk - 2; t += 2) {
        WAIT_VM4; BAR;                // buf0 (tile t) landed everywhere
        compute(As0, Bs0);
        BAR;                          // all waves done reading buf0
        stage(As0, Bs0, k0); k0 += 32;        // tile t+2 -> buf0

        WAIT_VM4; BAR;                // buf1 (tile t+1) landed
        compute(As1, Bs1);
        BAR;
        stage(As1, Bs1, k0); k0 += 32;        // tile t+3 -> buf1
    }
    WAIT_VM4; BAR;                    // tile nk-2
    compute(As0, Bs0);
    WAIT_VM0; BAR;                    // tile nk-1
    compute(As1, Bs1);

    // epilogue: C/D layout col=lane&15, row=quad*4+reg  [m89/m91 verified]
#pragma unroll
    for (int i = 0; i < 4; ++i) {
#pragma unroll
        for (int j = 0; j < 4; ++j) {
            const long r0 = row0 + wm + i * 16 + quad * 4;
            const long c  = col0 + wn + j * 16 + l16;
            const float bb = bias ? bias[c] : 0.0f;
#pragma unroll
            for (int r = 0; r < 4; ++r) {
                const float v = acc[i][j][r] * scale + bb;
                const long rr = r0 + r;
                if (Cb) {
                    if (transC) {
                        Cb[((rr >> 10) * 768 + c) * 1024 + (rr & 1023)] = f2bf(v);
                    } else {
                        Cb[rr * ldc + c] = f2bf(v);
                    }
                } else {
                    Cf[rr * ldc + c] = v;
                }
            }
        }
    }
}

// ---------------------------------------------------------------------------

__global__ __launch_bounds__(256, 4) void proj_qkv(
    const unsigned short* __restrict__ xb, const unsigned short* __restrict__ eb,
    const unsigned short* __restrict__ wqt, const unsigned short* __restrict__ wkt,
    const unsigned short* __restrict__ wvt,
    const float* __restrict__ bq, const float* __restrict__ bk,
    const float* __restrict__ bv,
    unsigned short* __restrict__ q, unsigned short* __restrict__ k,
    unsigned short* __restrict__ vt)
{
    const unsigned short *A, *Bt; const float* bias; unsigned short* C;
    int trans = 0;
    switch (blockIdx.z) {
        case 0:  A = xb; Bt = wqt; bias = bq; C = q;  break;
        case 1:  A = eb; Bt = wkt; bias = bk; C = k;  break;
        default: A = eb; Bt = wvt; bias = bv; C = vt; trans = 1; break;
    }
    const long row0 = (long)blockIdx.x * 128;
    const long col0 = (long)blockIdx.y * 128;
    gemm_core(A + row0 * 768, Bt + col0 * 768, 768,
              nullptr, C, 768, trans, bias, 1.0f, row0, col0);
}

__global__ __launch_bounds__(256, 4) void scores_gemm(
    const unsigned short* __restrict__ q, const unsigned short* __restrict__ k,
    float* __restrict__ sc, float scale)
{
    const long b    = blockIdx.z;
    const long row0 = (long)blockIdx.x * 128;    // within batch
    const long col0 = (long)blockIdx.y * 128;
    gemm_core(q + (b * 1024 + row0) * 768, k + b * 786432 + col0 * 768, 768,
              sc + b * 1048576, nullptr, 1024, 0, nullptr, scale, row0, col0);
}

__global__ __launch_bounds__(256, 4) void pv_gemm(
    const unsigned short* __restrict__ p, const unsigned short* __restrict__ vt,
    unsigned short* __restrict__ ao)
{
    const long b    = blockIdx.z;
    const long row0 = (long)blockIdx.x * 128;    // within batch
    const long col0 = (long)blockIdx.y * 128;
    gemm_core(p + (b * 1024 + row0) * 1024, vt + b * 786432 + col0 * 1024, 1024,
              nullptr, ao + b * 786432, 768, 0, nullptr, 1.0f, row0, col0);
}

__global__ __launch_bounds__(256, 4) void outproj_gemm(
    const unsigned short* __restrict__ ao, const unsigned short* __restrict__ wpt,
    float* __restrict__ out, const float* __restrict__ bp)
{
    const long row0 = (long)blockIdx.x * 128;
    const long col0 = (long)blockIdx.y * 128;
    gemm_core(ao + row0 * 768, wpt + col0 * 768, 768,
              out, nullptr, 768, 0, bp, 1.0f, row0, col0);
}

// ---------------------------------------------------------------------------

__global__ __launch_bounds__(256) void convert_inputs(
    const float* __restrict__ x, const float* __restrict__ enc,
    unsigned short* __restrict__ xb, unsigned short* __restrict__ eb, int nper)
{
    const int i = blockIdx.x * 256 + threadIdx.x;   // float4 index
    const bool second = (i >= nper);
    const int idx = second ? i - nper : i;
    const float4 v = second ? ((const float4*)enc)[idx] : ((const float4*)x)[idx];
    ushort4 o;
    o.x = f2bf(v.x); o.y = f2bf(v.y); o.z = f2bf(v.z); o.w = f2bf(v.w);
    if (second) ((ushort4*)eb)[idx] = o;
    else        ((ushort4*)xb)[idx] = o;
}

__global__ __launch_bounds__(256) void transpose_w(
    const float* __restrict__ w0, const float* __restrict__ w1,
    const float* __restrict__ w2, const float* __restrict__ w3,
    unsigned short* __restrict__ o0, unsigned short* __restrict__ o1,
    unsigned short* __restrict__ o2, unsigned short* __restrict__ o3)
{
    const float* w; unsigned short* o;
    switch (blockIdx.z) {
        case 0:  w = w0; o = o0; break;
        case 1:  w = w1; o = o1; break;
        case 2:  w = w2; o = o2; break;
        default: w = w3; o = o3; break;
    }
    __shared__ float t[32][33];
    const int tx = threadIdx.x & 31;
    const int ty = threadIdx.x >> 5;          // 0..7
    const int k0 = blockIdx.x * 32;
    const int n0 = blockIdx.y * 32;
#pragma unroll
    for (int i = 0; i < 4; ++i)
        t[ty + i * 8][tx] = w[(long)(k0 + ty + i * 8) * 768 + n0 + tx];
    __syncthreads();
#pragma unroll
    for (int i = 0; i < 4; ++i)
        o[(long)(n0 + ty + i * 8) * 768 + k0 + tx] = f2bf(t[tx][ty + i * 8]);
}

__global__ __launch_bounds__(256) void softmax_rows(
    const float* __restrict__ S, unsigned short* __restrict__ P)
{
    const long row = blockIdx.x;                 // 8192 rows of 1024
    const float* s = S + row * 1024;
    unsigned short* p = P + row * 1024;
    const int tid  = threadIdx.x;
    const int lane = tid & 63;
    const int wave = tid >> 6;

    float4 v = ((const float4*)s)[tid];
    float m = fmaxf(fmaxf(v.x, v.y), fmaxf(v.z, v.w));
#pragma unroll
    for (int off = 32; off > 0; off >>= 1)
        m = fmaxf(m, __shfl_xor(m, off));
    __shared__ float redm[4], reds[4];
    if (lane == 0) redm[wave] = m;
    __syncthreads();
    m = fmaxf(fmaxf(redm[0], redm[1]), fmaxf(redm[2], redm[3]));

    const float e0 = __expf(v.x - m), e1 = __expf(v.y - m);
    const float e2 = __expf(v.z - m), e3 = __expf(v.w - m);
    float sum = e0 + e1 + e2 + e3;
#pragma unroll
    for (int off = 32; off > 0; off >>= 1)
        sum += __shfl_xor(sum, off);
    if (lane == 0) reds[wave] = sum;
    __syncthreads();
    const float inv = 1.0f / (reds[0] + reds[1] + reds[2] + reds[3]);

    ushort4 o;
    o.x = f2bf(e0 * inv); o.y = f2bf(e1 * inv);
    o.z = f2bf(e2 * inv); o.w = f2bf(e3 * inv);
    ((ushort4*)p)[tid] = o;
}

// ---------------------------------------------------------------------------

extern "C" void kernel_launch(void* const* d_in, const int* in_sizes, int n_in,
                              void* d_out, int out_size, void* d_ws, size_t ws_size,
                              hipStream_t stream) {
    const float* x   = (const float*)d_in[0];
    const float* enc = (const float*)d_in[1];
    const float* Wq  = (const float*)d_in[2];
    const float* bq  = (const float*)d_in[3];
    const float* Wk  = (const float*)d_in[4];
    const float* bk  = (const float*)d_in[5];
    const float* Wv  = (const float*)d_in[6];
    const float* bv  = (const float*)d_in[7];
    const float* Wp  = (const float*)d_in[8];
    const float* bp  = (const float*)d_in[9];
    float* out = (float*)d_out;

    // workspace layout (bytes); peak need ~101.2 MB
    char* ws = (char*)d_ws;
    unsigned short* xb  = (unsigned short*)(ws + 0);         // 12582912
    unsigned short* eb  = (unsigned short*)(ws + 12582912);  // 12582912
    unsigned short* q   = (unsigned short*)(ws + 25165824);  // 12582912
    unsigned short* k   = (unsigned short*)(ws + 37748736);  // 12582912
    unsigned short* vt  = (unsigned short*)(ws + 50331648);  // 12582912 [B][H][S]
    unsigned short* wqt = (unsigned short*)(ws + 62914560);  // 1179648
    unsigned short* wkt = (unsigned short*)(ws + 64094208);  // 1179648
    unsigned short* wvt = (unsigned short*)(ws + 65273856);  // 1179648
    unsigned short* wpt = (unsigned short*)(ws + 66453504);  // 1179648
    float*          sc  = (float*)(ws + 67633152);           // 33554432 fp32 scores
    unsigned short* p   = (unsigned short*)(ws + 0);         // 16777216, overlays xb/eb (dead)
    unsigned short* ao  = (unsigned short*)(ws + 67633152);  // 12582912, overlays sc (dead)

    const float scale = 0.03608439182435161f;  // 1/sqrt(768)

    // 1. fp32 -> bf16 for x and encoder_out
    convert_inputs<<<12288, 256, 0, stream>>>(x, enc, xb, eb, 1572864);

    // 2. W^T bf16 for all four weights
    transpose_w<<<dim3(24, 24, 4), 256, 0, stream>>>(Wq, Wk, Wv, Wp, wqt, wkt, wvt, wpt);

    // 3. q/k/v projections: 128x128 tiles
    proj_qkv<<<dim3(64, 6, 3), 256, 0, stream>>>(xb, eb, wqt, wkt, wvt, bq, bk, bv, q, k, vt);

    // 4. scores = q k^T * scale (fp32)
    scores_gemm<<<dim3(8, 8, 8), 256, 0, stream>>>(q, k, sc, scale);

    // 5. softmax rows -> bf16 P
    softmax_rows<<<8192, 256, 0, stream>>>(sc, p);

    // 6. ao = P @ V
    pv_gemm<<<dim3(8, 6, 8), 256, 0, stream>>>(p, vt, ao);

    // 7. out = ao @ Wp + bp
    outproj_gemm<<<dim3(64, 6, 1), 256, 0, stream>>>(ao, wpt, out, bp);
}